// Round 12
// baseline (1961.128 us; speedup 1.0000x reference)
//
#include <hip/hip_runtime.h>
#include <hip/hip_cooperative_groups.h>
#include <hip/hip_fp16.h>

namespace cg = cooperative_groups;

#define Nn 100000
#define Ee 800000
#define Dd 16
#define Hh 128
#define Oo 3
#define Rr 2
#define HROW 256      // fp16 H row: 256 halves = [h_b0(128) | h_b1(128)]
#define Mm (Rr * Nn)
#define CNTB ((Ee + 255) / 256)                        // 3125 place virtual-blocks
#define SWB 48
#define INTB2 ((Nn + 255) / 256)                       // 391 input virtual-blocks
#define PREPB (INTB2 + CNTB + SWB)                     // 3564
#define FN 16         // nodes per conv tile
#define NTILES (Nn / FN)                               // 6250
#define MPAD 516      // LDS M-row stride (halves)
#define OPAD 264      // LDS out-row stride for fused projection
#define NZ16 ((Mm * 4 + 512) / 16)                     // int4 count for cnt+zero-row
#define NBLK 1536     // 6 blocks/CU x 256 CU (guaranteed by lb(256,6) + 20KB LDS)

typedef _Float16 half8 __attribute__((ext_vector_type(8)));
typedef float floatx4 __attribute__((ext_vector_type(4)));

// ---------------- diagnostic ----------------
__global__ void k_diag(float* out, float v) { out[0] = v; }

// ================= prep body (r11-verbatim math; shared by mega + fallback) =================
__device__ __forceinline__ void prep_body(
    int bx, int tid,
    const int* __restrict__ ei, const int* __restrict__ et,
    int* __restrict__ cnt, int* __restrict__ eidx, int cap,
    const float* __restrict__ r1root, const float* __restrict__ r1w,
    const float* __restrict__ r2root, const float* __restrict__ r2w,
    __half* __restrict__ Bsw1, __half* __restrict__ Bsw2,
    const float* __restrict__ mf, const float* __restrict__ ff,
    const float* __restrict__ W1T, const float* __restrict__ b1,
    __half* __restrict__ H) {
    if (bx < INTB2) {
        // ---- input layer: node-in-lane (r7-proven) ----
        int n = bx * 256 + tid;
        if (n < Nn) {
            float x0[Dd], x1[Dd];
            {
                const float4* m4 = (const float4*)(mf + (size_t)n * Dd);
                const float4* f4 = (const float4*)(ff + (size_t)n * Dd);
#pragma unroll
                for (int q = 0; q < 4; ++q) {
                    float4 a = m4[q];
                    float4 b = f4[q];
                    x0[q * 4 + 0] = a.x; x1[q * 4 + 0] = b.x - a.x;
                    x0[q * 4 + 1] = a.y; x1[q * 4 + 1] = b.y - a.y;
                    x0[q * 4 + 2] = a.z; x1[q * 4 + 2] = b.z - a.z;
                    x0[q * 4 + 3] = a.w; x1[q * 4 + 3] = b.w - a.w;
                }
            }
            __half* hrow = H + (size_t)n * HROW;
            for (int j8 = 0; j8 < 16; ++j8) {
                half8 o0, o1;
#pragma unroll
                for (int jj = 0; jj < 8; ++jj) {
                    int j = j8 * 8 + jj;
                    const float* wr = W1T + j * Dd;       // wave-uniform -> s_load
                    float bj = b1[j];                     // wave-uniform
                    float a0 = bj, a1 = bj;
#pragma unroll
                    for (int k = 0; k < Dd; ++k) {
                        a0 = fmaf(x0[k], wr[k], a0);      // v_fma: 1 SGPR operand ok
                        a1 = fmaf(x1[k], wr[k], a1);
                    }
                    a0 = a0 > 0.f ? a0 : 0.01f * a0;
                    a1 = a1 > 0.f ? a1 : 0.01f * a1;
                    o0[jj] = (_Float16)a0;
                    o1[jj] = (_Float16)a1;
                }
                *(half8*)(void*)(hrow + j8 * 8) = o0;     // 16B stores, L2 merges
                *(half8*)(void*)(hrow + Hh + j8 * 8) = o1;
            }
        }
        return;
    }
    int sb = bx - INTB2;
    if (sb < CNTB) {
        // ---- direct placement: one edge per thread (r2-proven) ----
        int e = sb * 256 + tid;
        if (e < Ee) {
            int s = ei[e];
            int d = ei[Ee + e];
            int t = et[e];
            int gb = t * Nn + d;
            int pos = atomicAdd(&cnt[gb], 1);
            if (pos < cap) eidx[(size_t)gb * cap + pos] = s;
        }
        return;
    }
    sb -= CNTB;
    {
        // ---- weight swizzle for 16x16x32 MFMA (r5-verified mapping) ----
        const float* wroot = (sb < 24) ? r1root : r2root;
        const float* wrel = (sb < 24) ? r1w : r2w;
        __half* Bsw = (sb < 24) ? Bsw1 : Bsw2;
        int idx = (sb % 24) * 256 + tid;
        if (idx < 8 * 12 * 64) {
            int l = idx & 63;
            int s = (idx >> 6) % 12;
            int t = (idx >> 6) / 12;
            int n = (l & 15) * 8 + t;
            int k0 = s * 32 + (l >> 4) * 8;
            __half tmp[8];
#pragma unroll
            for (int jj = 0; jj < 8; ++jj) {
                int k = k0 + jj;
                float v = (k < Hh) ? wroot[k * Hh + n] : wrel[(size_t)(k - Hh) * Hh + n];
                tmp[jj] = __float2half(v);
            }
            *(uint4*)(Bsw + (size_t)idx * 8) = *(uint4*)tmp;
        }
    }
}

// ================= conv tile loop (r11-verbatim math; shared by mega + fallback) =================
__device__ __forceinline__ void conv_tiles(
    int tile0, int tileEnd, int tstep,
    char* smemc, float* WoS, float* bS,
    const __half* __restrict__ Hin, __half* __restrict__ Hout,
    const int* __restrict__ cnt, const int* __restrict__ eidx, int cap,
    const __half* __restrict__ Bsw, const float* __restrict__ bias,
    const __half* __restrict__ zrow, int do_final,
    const float* __restrict__ Wo, const float* __restrict__ bo,
    float* __restrict__ out) {
    auto TM = (__half(*)[MPAD])smemc;
    auto TO = (__half(*)[OPAD])smemc;
    int tid = threadIdx.x;
    int wv = tid >> 6;
    int lane = tid & 63;

    if (do_final) {
        for (int i = tid; i < Hh * Oo; i += 256) WoS[i] = Wo[i];
        if (tid < Oo) bS[tid] = bo[tid];
    }

    int hh32 = lane >> 5;      // half-wave id == relation t
    int sl = lane & 31;        // sublane within half-wave
    const __half* zr = zrow + sl * 8;

    for (int tile = tile0; tile < tileEnd; tile += tstep) {
        __syncthreads();       // protect TM/TO reuse across grid-strided tiles
        int n0 = tile * FN;

        // ---- Phase A (r5 paired-bucket structure) ----
        int cn0[4], cn1[4], sidx[4];
#pragma unroll
        for (int p = 0; p < 4; ++p) {
            int gb0 = n0 + wv * 4 + p;                   // relation-0 bucket
            cn0[p] = cnt[gb0];
            cn1[p] = cnt[gb0 + Nn];
            sidx[p] = eidx[(size_t)(hh32 * Nn + gb0) * cap + sl];
        }

#pragma unroll
        for (int pp = 0; pp < 4; pp += 2) {
            int pA = pp, pB = pp + 1;
            int cnA = hh32 ? cn1[pA] : cn0[pA];
            int cnB = hh32 ? cn1[pB] : cn0[pB];
            int lenA = cnA < 32 ? cnA : 32;
            int lenB = cnB < 32 ? cnB : 32;
            int mA = cn0[pA] > cn1[pA] ? cn0[pA] : cn1[pA];
            int mB = cn0[pB] > cn1[pB] ? cn0[pB] : cn1[pB];
            int maxA = mA < 32 ? mA : 32;
            int maxB = mB < 32 ? mB : 32;

            int bA0 = __shfl(sidx[pA], 0, 32), bA1 = __shfl(sidx[pA], 1, 32);
            int bA2 = __shfl(sidx[pA], 2, 32), bA3 = __shfl(sidx[pA], 3, 32);
            int bB0 = __shfl(sidx[pB], 0, 32), bB1 = __shfl(sidx[pB], 1, 32);
            int bB2 = __shfl(sidx[pB], 2, 32), bB3 = __shfl(sidx[pB], 3, 32);

            half8 vA0 = *(const half8*)(const void*)((0 < lenA) ? Hin + (size_t)bA0 * HROW + sl * 8 : zr);
            half8 vA1 = *(const half8*)(const void*)((1 < lenA) ? Hin + (size_t)bA1 * HROW + sl * 8 : zr);
            half8 vA2 = *(const half8*)(const void*)((2 < lenA) ? Hin + (size_t)bA2 * HROW + sl * 8 : zr);
            half8 vA3 = *(const half8*)(const void*)((3 < lenA) ? Hin + (size_t)bA3 * HROW + sl * 8 : zr);
            half8 vB0 = *(const half8*)(const void*)((0 < lenB) ? Hin + (size_t)bB0 * HROW + sl * 8 : zr);
            half8 vB1 = *(const half8*)(const void*)((1 < lenB) ? Hin + (size_t)bB1 * HROW + sl * 8 : zr);
            half8 vB2 = *(const half8*)(const void*)((2 < lenB) ? Hin + (size_t)bB2 * HROW + sl * 8 : zr);
            half8 vB3 = *(const half8*)(const void*)((3 < lenB) ? Hin + (size_t)bB3 * HROW + sl * 8 : zr);

            float2 acA[4], acB[4];
#pragma unroll
            for (int j = 0; j < 4; ++j) {
                acA[j].x = 0.f; acA[j].y = 0.f;
                acB[j].x = 0.f; acB[j].y = 0.f;
            }
#pragma unroll
            for (int j = 0; j < 4; ++j) {
                acA[j].x += (float)vA0[2 * j] + (float)vA1[2 * j] + (float)vA2[2 * j] + (float)vA3[2 * j];
                acA[j].y += (float)vA0[2 * j + 1] + (float)vA1[2 * j + 1] + (float)vA2[2 * j + 1] + (float)vA3[2 * j + 1];
                acB[j].x += (float)vB0[2 * j] + (float)vB1[2 * j] + (float)vB2[2 * j] + (float)vB3[2 * j];
                acB[j].y += (float)vB0[2 * j + 1] + (float)vB1[2 * j + 1] + (float)vB2[2 * j + 1] + (float)vB3[2 * j + 1];
            }

            if (maxA > 4) {
                for (int e = 4; e < maxA; e += 4) {
                    half8 v[4];
#pragma unroll
                    for (int u = 0; u < 4; ++u) {
                        int s_ = __shfl(sidx[pA], e + u, 32);
                        v[u] = *(const half8*)(const void*)(
                            ((e + u) < lenA) ? Hin + (size_t)s_ * HROW + sl * 8 : zr);
                    }
#pragma unroll
                    for (int u = 0; u < 4; ++u) {
#pragma unroll
                        for (int j = 0; j < 4; ++j) {
                            acA[j].x += (float)v[u][2 * j];
                            acA[j].y += (float)v[u][2 * j + 1];
                        }
                    }
                }
            }
            if (maxB > 4) {
                for (int e = 4; e < maxB; e += 4) {
                    half8 v[4];
#pragma unroll
                    for (int u = 0; u < 4; ++u) {
                        int s_ = __shfl(sidx[pB], e + u, 32);
                        v[u] = *(const half8*)(const void*)(
                            ((e + u) < lenB) ? Hin + (size_t)s_ * HROW + sl * 8 : zr);
                    }
#pragma unroll
                    for (int u = 0; u < 4; ++u) {
#pragma unroll
                        for (int j = 0; j < 4; ++j) {
                            acB[j].x += (float)v[u][2 * j];
                            acB[j].y += (float)v[u][2 * j + 1];
                        }
                    }
                }
            }

            float ivA = 1.0f / fmaxf((float)cnA, 1.0f);
            float ivB = 1.0f / fmaxf((float)cnB, 1.0f);
            __half2 oA[4], oB[4];
#pragma unroll
            for (int j = 0; j < 4; ++j) {
                oA[j] = __floats2half2_rn(acA[j].x * ivA, acA[j].y * ivA);
                oB[j] = __floats2half2_rn(acB[j].x * ivB, acB[j].y * ivB);
            }
            __half* dA = &TM[wv * 4 + pA][hh32 * 256 + sl * 8];   // 1032B stride: 8B-aligned
            __half* dB = &TM[wv * 4 + pB][hh32 * 256 + sl * 8];
            *(uint2*)dA = *(uint2*)&oA[0];
            *(uint2*)(dA + 4) = *(uint2*)&oA[2];
            *(uint2*)dB = *(uint2*)&oB[0];
            *(uint2*)(dB + 4) = *(uint2*)&oB[2];
        }
        __syncthreads();

        // ---- Phase B: MFMA. wave -> branch b = wv>>1, col-half hh = wv&1 ----
        int b = wv >> 1;
        int hh = wv & 1;
        int quad = lane >> 4;
        int l15 = lane & 15;

        floatx4 acc[4];
#pragma unroll
        for (int t = 0; t < 4; ++t) {
            float bv = bias[l15 * 8 + hh * 4 + t];
            acc[t][0] = bv; acc[t][1] = bv; acc[t][2] = bv; acc[t][3] = bv;
        }

        const __half* hrow = Hin + (size_t)(n0 + l15) * HROW + b * Hh + quad * 8;
#pragma unroll
        for (int s = 0; s < 12; ++s) {
            half8 af;
            if (s < 4)
                af = *(const half8*)(const void*)(hrow + s * 32);
            else
                af = *(const half8*)(const void*)&TM[l15][((s >> 2) - 1) * 256 + b * 128 +
                                                         (s & 3) * 32 + quad * 8];
#pragma unroll
            for (int t = 0; t < 4; ++t) {
                half8 bf = *(const half8*)(const void*)(
                    Bsw + ((size_t)((hh * 4 + t) * 12 + s) * 64 + lane) * 8);
                acc[t] = __builtin_amdgcn_mfma_f32_16x16x32_f16(af, bf, acc[t], 0, 0, 0);
            }
        }

        if (!do_final) {
#pragma unroll
            for (int r = 0; r < 4; ++r) {
                int node = n0 + quad * 4 + r;
                __half2 o[2];
                o[0] = __floats2half2_rn(acc[0][r], acc[1][r]);
                o[1] = __floats2half2_rn(acc[2][r], acc[3][r]);
                *(uint2*)(Hout + (size_t)node * HROW + b * Hh + l15 * 8 + hh * 4) = *(uint2*)o;
            }
        } else {
            __syncthreads();  // all TM reads done before aliased TO writes
#pragma unroll
            for (int r = 0; r < 4; ++r) {
                int nl = quad * 4 + r;
                __half2 o[2];
                o[0] = __floats2half2_rn(acc[0][r], acc[1][r]);
                o[1] = __floats2half2_rn(acc[2][r], acc[3][r]);
                *(uint2*)&TO[nl][b * 128 + l15 * 8 + hh * 4] = *(uint2*)o;
            }
            __syncthreads();
            if (tid < FN * Oo) {
                int node = tid / 3;
                int o3 = tid - node * 3;
                float a = bS[o3], m = bS[o3];
                const __half2* row = (const __half2*)TO[node];
#pragma unroll 4
                for (int k2 = 0; k2 < 64; ++k2) {
                    float2 v = __half22float2(row[k2]);
                    float2 u = __half22float2(row[64 + k2]);
                    float w0 = WoS[(2 * k2) * 3 + o3];
                    float w1 = WoS[(2 * k2 + 1) * 3 + o3];
                    a += v.x * w0 + v.y * w1;
                    m += u.x * w0 + u.y * w1;
                }
                out[(size_t)(n0 + node) * 3 + o3] = a * m;
            }
        }
    }
}

// ================= cooperative mega-kernel: init -> prep -> conv1 -> conv2 =================
__global__ __launch_bounds__(256, 6) void k_mega(
    const int* ei, const int* et, int* cnt, int* eidx, int cap,
    const float* r1root, const float* r1w, const float* r2root, const float* r2w,
    __half* Bsw1, __half* Bsw2,
    const float* mf, const float* ff,
    const float* W1, const float* b1, float* W1T,
    __half* H0, __half* H1, const __half* zrow,
    const float* rg1_b, const float* rg2_b,
    const float* Wo, const float* bo, float* out, int nblk) {
    __shared__ __align__(16) char smem[FN * MPAD * 2];   // 16512 B
    __shared__ float WoS[Hh * Oo];
    __shared__ float bS[Oo];
    cg::grid_group grid = cg::this_grid();
    int tid = threadIdx.x;
    int bid = blockIdx.x;

    // phase 0: zero cnt+zrow, transpose W1
    for (int idx = bid * 256 + tid; idx < NZ16; idx += nblk * 256)
        ((int4*)cnt)[idx] = make_int4(0, 0, 0, 0);
    if (bid == 0 && tid < Hh) {
#pragma unroll
        for (int k = 0; k < Dd; ++k) W1T[tid * Dd + k] = W1[k * Hh + tid];
    }
    grid.sync();

    // phase 1: prep (grid-stride over 3564 virtual blocks)
    for (int vb = bid; vb < PREPB; vb += nblk)
        prep_body(vb, tid, ei, et, cnt, eidx, cap, r1root, r1w, r2root, r2w,
                  Bsw1, Bsw2, mf, ff, W1T, b1, H0);
    grid.sync();

    // phase 2: conv1
    conv_tiles(bid, NTILES, nblk, smem, WoS, bS, H0, H1, cnt, eidx, cap,
               Bsw1, rg1_b, zrow, 0, nullptr, nullptr, nullptr);
    grid.sync();

    // phase 3: conv2 + fused projection
    conv_tiles(bid, NTILES, nblk, smem, WoS, bS, H1, H0, cnt, eidx, cap,
               Bsw2, rg2_b, zrow, 1, Wo, bo, out);
}

// ================= fallback kernels (proven r11 4-dispatch pipeline) =================
__global__ __launch_bounds__(256) void k_init(int4* __restrict__ z,
                                              const float* __restrict__ W1,
                                              float* __restrict__ W1T) {
    int idx = blockIdx.x * 256 + threadIdx.x;
    if (idx < NZ16) z[idx] = make_int4(0, 0, 0, 0);
    if (blockIdx.x == 0 && threadIdx.x < Hh) {
        int j = threadIdx.x;
#pragma unroll
        for (int k = 0; k < Dd; ++k) W1T[j * Dd + k] = W1[k * Hh + j];
    }
}

__global__ __launch_bounds__(256) void k_prep_all(
    const int* ei, const int* et, int* cnt, int* eidx, int cap,
    const float* r1root, const float* r1w, const float* r2root, const float* r2w,
    __half* Bsw1, __half* Bsw2, const float* mf, const float* ff,
    const float* W1T, const float* b1, __half* H) {
    prep_body(blockIdx.x, threadIdx.x, ei, et, cnt, eidx, cap, r1root, r1w,
              r2root, r2w, Bsw1, Bsw2, mf, ff, W1T, b1, H);
}

__global__ __launch_bounds__(256, 6) void k_conv_f(const __half* Hin, __half* Hout,
                                                   const int* cnt, const int* eidx, int cap,
                                                   const __half* Bsw, const float* bias,
                                                   const __half* zrow, int do_final,
                                                   const float* Wo, const float* bo,
                                                   float* out) {
    __shared__ __align__(16) char smem[FN * MPAD * 2];
    __shared__ float WoS[Hh * Oo];
    __shared__ float bS[Oo];
    conv_tiles(blockIdx.x, blockIdx.x + 1, 1, smem, WoS, bS, Hin, Hout, cnt, eidx,
               cap, Bsw, bias, zrow, do_final, Wo, bo, out);
}

// ================= host =================
extern "C" void kernel_launch(void* const* d_in, const int* in_sizes, int n_in,
                              void* d_out, int out_size, void* d_ws, size_t ws_size,
                              hipStream_t stream) {
    const float* mf = (const float*)d_in[0];
    const float* ff = (const float*)d_in[1];
    const float* W1 = (const float*)d_in[2];
    const float* b1 = (const float*)d_in[3];
    const float* rg1_w = (const float*)d_in[4];
    const float* rg1_root = (const float*)d_in[5];
    const float* rg1_b = (const float*)d_in[6];
    const float* rg2_w = (const float*)d_in[7];
    const float* rg2_root = (const float*)d_in[8];
    const float* rg2_b = (const float*)d_in[9];
    const float* Wo = (const float*)d_in[10];
    const float* bo = (const float*)d_in[11];
    const int* ei = (const int*)d_in[12];
    const int* et = (const int*)d_in[13];
    float* out = (float*)d_out;

    const size_t szBsw = (size_t)8 * 12 * 64 * 8 * 2;  // 96 KB

    auto layoutNeed = [&](int cap, size_t* offs) {
        size_t o = 0;
        auto take = [&](size_t bytes) { size_t r = o; o += (bytes + 15) & ~(size_t)15; return r; };
        offs[0] = take((size_t)Mm * 4 + 512);        // cnt + zero-row
        offs[1] = take((size_t)Mm * cap * 4);        // eidx (fixed-capacity buckets)
        offs[2] = take(szBsw);                       // Bsw1
        offs[3] = take(szBsw);                       // Bsw2
        offs[4] = take((size_t)Nn * HROW * 2);       // H0
        offs[5] = take((size_t)Nn * HROW * 2);       // H1
        offs[6] = take((size_t)Hh * Dd * 4);         // W1T (8 KB)
        return o;
    };

    size_t offs[7];
    int cap = 64;                                    // ~154.7 MB (proven ws >= ~159.6 MB)
    size_t NEED = layoutNeed(cap, offs);
    if (ws_size < NEED) {
        cap = 32;
        NEED = layoutNeed(cap, offs);
        if (ws_size < NEED) {
            k_diag<<<1, 1, 0, stream>>>(out, (float)ws_size);
            return;
        }
    }

    int* cnt = (int*)((char*)d_ws + offs[0]);
    int* eidx = (int*)((char*)d_ws + offs[1]);
    __half* Bsw1 = (__half*)((char*)d_ws + offs[2]);
    __half* Bsw2 = (__half*)((char*)d_ws + offs[3]);
    __half* H0 = (__half*)((char*)d_ws + offs[4]);
    __half* H1 = (__half*)((char*)d_ws + offs[5]);
    float* W1T = (float*)((char*)d_ws + offs[6]);
    const __half* zrow = (const __half*)((char*)d_ws + offs[0] + (size_t)Mm * 4);

    // ---- single cooperative dispatch (3 grid syncs); fallback = proven 4-dispatch ----
    int nblk = NBLK;
    void* kargs[] = {
        (void*)&ei, (void*)&et, (void*)&cnt, (void*)&eidx, (void*)&cap,
        (void*)&rg1_root, (void*)&rg1_w, (void*)&rg2_root, (void*)&rg2_w,
        (void*)&Bsw1, (void*)&Bsw2, (void*)&mf, (void*)&ff,
        (void*)&W1, (void*)&b1, (void*)&W1T,
        (void*)&H0, (void*)&H1, (void*)&zrow,
        (void*)&rg1_b, (void*)&rg2_b,
        (void*)&Wo, (void*)&bo, (void*)&out, (void*)&nblk};
    hipError_t err = hipLaunchCooperativeKernel((const void*)k_mega, dim3(NBLK),
                                                dim3(256), kargs, 0, stream);
    if (err != hipSuccess) {
        k_init<<<(NZ16 + 255) / 256, 256, 0, stream>>>((int4*)cnt, W1, W1T);
        k_prep_all<<<PREPB, 256, 0, stream>>>(ei, et, cnt, eidx, cap,
                                              rg1_root, rg1_w, rg2_root, rg2_w,
                                              Bsw1, Bsw2, mf, ff, W1T, b1, H0);
        k_conv_f<<<NTILES, 256, 0, stream>>>(H0, H1, cnt, eidx, cap, Bsw1, rg1_b, zrow,
                                             0, nullptr, nullptr, nullptr);
        k_conv_f<<<NTILES, 256, 0, stream>>>(H1, H0, cnt, eidx, cap, Bsw2, rg2_b, zrow,
                                             1, Wo, bo, out);
    }
}

// Round 13
// 330.139 us; speedup vs baseline: 5.9403x; 5.9403x over previous
//
#include <hip/hip_runtime.h>
#include <hip/hip_fp16.h>

#define Nn 100000
#define Ee 800000
#define Dd 16
#define Hh 128
#define Oo 3
#define Rr 2
#define HROW 256      // fp16 H row: 256 halves = [h_b0(128) | h_b1(128)]
#define Mm (Rr * Nn)
#define CNTB ((Ee + 255) / 256)                        // 3125 place blocks
#define SWB 48
#define INTB2 ((Nn + 255) / 256)                       // 391 input blocks (node-in-lane)
#define FN 16         // nodes per fused-conv block
#define MPAD 516      // LDS M-row stride (halves)
#define OPAD 264      // LDS out-row stride for fused projection
#define NZ16 ((Mm * 4 + 512) / 16)                     // int4 count for cnt+zero-row

typedef _Float16 half8 __attribute__((ext_vector_type(8)));
typedef float floatx4 __attribute__((ext_vector_type(4)));

// ---------------- diagnostic ----------------
__global__ void k_diag(float* out, float v) { out[0] = v; }

// ---------------- init: zero cnt+zrow AND transpose W1 (one dispatch) ----------------
__global__ __launch_bounds__(256) void k_init(int4* __restrict__ z,
                                              const float* __restrict__ W1,
                                              float* __restrict__ W1T) {
    int idx = blockIdx.x * 256 + threadIdx.x;
    if (idx < NZ16) z[idx] = make_int4(0, 0, 0, 0);
    if (blockIdx.x == 0 && threadIdx.x < Hh) {
        int j = threadIdx.x;
#pragma unroll
        for (int k = 0; k < Dd; ++k) W1T[j * Dd + k] = W1[k * Hh + j];
    }
}

// ================= fused prep: input | place | swizzle (input FIRST — r10 lesson:
// place-first thrashes L2 -> input H-lines evicted partial -> write amplification) =================
__global__ __launch_bounds__(256) void k_prep_all(
    const int* __restrict__ ei, const int* __restrict__ et,
    int* __restrict__ cnt, int* __restrict__ eidx, int cap,
    const float* __restrict__ r1root, const float* __restrict__ r1w,
    const float* __restrict__ r2root, const float* __restrict__ r2w,
    __half* __restrict__ Bsw1, __half* __restrict__ Bsw2,
    const float* __restrict__ mf, const float* __restrict__ ff,
    const float* __restrict__ W1T, const float* __restrict__ b1,
    __half* __restrict__ H) {
    int tid = threadIdx.x;
    int bx = blockIdx.x;

    if (bx < INTB2) {
        // ---- input layer: node-in-lane (r7-proven) ----
        int n = bx * 256 + tid;
        if (n >= Nn) return;
        float x0[Dd], x1[Dd];
        {
            const float4* m4 = (const float4*)(mf + (size_t)n * Dd);
            const float4* f4 = (const float4*)(ff + (size_t)n * Dd);
#pragma unroll
            for (int q = 0; q < 4; ++q) {
                float4 a = m4[q];
                float4 b = f4[q];
                x0[q * 4 + 0] = a.x; x1[q * 4 + 0] = b.x - a.x;
                x0[q * 4 + 1] = a.y; x1[q * 4 + 1] = b.y - a.y;
                x0[q * 4 + 2] = a.z; x1[q * 4 + 2] = b.z - a.z;
                x0[q * 4 + 3] = a.w; x1[q * 4 + 3] = b.w - a.w;
            }
        }
        __half* hrow = H + (size_t)n * HROW;
        for (int j8 = 0; j8 < 16; ++j8) {
            half8 o0, o1;
#pragma unroll
            for (int jj = 0; jj < 8; ++jj) {
                int j = j8 * 8 + jj;
                const float* wr = W1T + j * Dd;       // wave-uniform -> s_load
                float bj = b1[j];                     // wave-uniform
                float a0 = bj, a1 = bj;
#pragma unroll
                for (int k = 0; k < Dd; ++k) {
                    a0 = fmaf(x0[k], wr[k], a0);      // v_fma: 1 SGPR operand ok
                    a1 = fmaf(x1[k], wr[k], a1);
                }
                a0 = a0 > 0.f ? a0 : 0.01f * a0;
                a1 = a1 > 0.f ? a1 : 0.01f * a1;
                o0[jj] = (_Float16)a0;
                o1[jj] = (_Float16)a1;
            }
            *(half8*)(void*)(hrow + j8 * 8) = o0;           // 16B stores, L2 merges
            *(half8*)(void*)(hrow + Hh + j8 * 8) = o1;
        }
        return;
    }
    int sb = bx - INTB2;
    if (sb < CNTB) {
        // ---- direct placement: one edge per thread (r2-proven) ----
        int e = sb * 256 + tid;
        if (e < Ee) {
            int s = ei[e];
            int d = ei[Ee + e];
            int t = et[e];
            int gb = t * Nn + d;
            int pos = atomicAdd(&cnt[gb], 1);
            if (pos < cap) eidx[(size_t)gb * cap + pos] = s;
        }
        return;
    }
    sb -= CNTB;
    {
        // ---- weight swizzle for 16x16x32 MFMA (r5-verified mapping) ----
        const float* wroot = (sb < 24) ? r1root : r2root;
        const float* wrel = (sb < 24) ? r1w : r2w;
        __half* Bsw = (sb < 24) ? Bsw1 : Bsw2;
        int idx = (sb % 24) * 256 + tid;
        if (idx >= 8 * 12 * 64) return;
        int l = idx & 63;
        int s = (idx >> 6) % 12;
        int t = (idx >> 6) / 12;
        int n = (l & 15) * 8 + t;
        int k0 = s * 32 + (l >> 4) * 8;
        __half tmp[8];
#pragma unroll
        for (int jj = 0; jj < 8; ++jj) {
            int k = k0 + jj;
            float v = (k < Hh) ? wroot[k * Hh + n] : wrel[(size_t)(k - Hh) * Hh + n];
            tmp[jj] = __float2half(v);
        }
        *(uint4*)(Bsw + (size_t)idx * 8) = *(uint4*)tmp;
    }
}

// ---------------- fused conv: reduction-free gather->LDS + MFMA (r5/r7 verbatim) ----
// Parked at measured service ceiling: 98us, FETCH pinned 224MB across 6 structural
// variants (MLP 4->8, occupancy 36-75%, both MFMA shapes, paired buckets); fp8
// byte-cut closed by accuracy threshold (r8/r9); cooperative fusion closed (r12:
// grid.sync + tile-striding -> FETCH 450MB->2GB, 6x slower).
__global__ __launch_bounds__(256, 6) void k_conv_f(const __half* __restrict__ Hin,
                                                   __half* __restrict__ Hout,
                                                   const int* __restrict__ cnt,
                                                   const int* __restrict__ eidx, int cap,
                                                   const __half* __restrict__ Bsw,
                                                   const float* __restrict__ bias,
                                                   const __half* __restrict__ zrow,
                                                   int do_final,
                                                   const float* __restrict__ Wo,
                                                   const float* __restrict__ bo,
                                                   float* __restrict__ out) {
    __shared__ __align__(16) char smem[FN * MPAD * 2];   // 16512 B; TM, later TO (aliased)
    __shared__ float WoS[Hh * Oo];
    __shared__ float bS[Oo];
    auto TM = (__half(*)[MPAD])smem;
    auto TO = (__half(*)[OPAD])smem;

    int tid = threadIdx.x;
    int n0 = blockIdx.x * FN;
    int wv = tid >> 6;
    int lane = tid & 63;

    if (do_final) {
        for (int i = tid; i < Hh * Oo; i += 256) WoS[i] = Wo[i];
        if (tid < Oo) bS[tid] = bo[tid];
    }

    // ---- Phase A ----
    int hh32 = lane >> 5;      // half-wave id == relation t
    int sl = lane & 31;        // sublane within half-wave
    const __half* zr = zrow + sl * 8;

    int cn0[4], cn1[4], sidx[4];
#pragma unroll
    for (int p = 0; p < 4; ++p) {
        int gb0 = n0 + wv * 4 + p;                       // relation-0 bucket
        cn0[p] = cnt[gb0];
        cn1[p] = cnt[gb0 + Nn];
        sidx[p] = eidx[(size_t)(hh32 * Nn + gb0) * cap + sl];
    }

#pragma unroll
    for (int pp = 0; pp < 4; pp += 2) {
        int pA = pp, pB = pp + 1;
        int cnA = hh32 ? cn1[pA] : cn0[pA];
        int cnB = hh32 ? cn1[pB] : cn0[pB];
        int lenA = cnA < 32 ? cnA : 32;
        int lenB = cnB < 32 ? cnB : 32;
        int mA = cn0[pA] > cn1[pA] ? cn0[pA] : cn1[pA];
        int mB = cn0[pB] > cn1[pB] ? cn0[pB] : cn1[pB];
        int maxA = mA < 32 ? mA : 32;
        int maxB = mB < 32 ? mB : 32;

        int bA0 = __shfl(sidx[pA], 0, 32), bA1 = __shfl(sidx[pA], 1, 32);
        int bA2 = __shfl(sidx[pA], 2, 32), bA3 = __shfl(sidx[pA], 3, 32);
        int bB0 = __shfl(sidx[pB], 0, 32), bB1 = __shfl(sidx[pB], 1, 32);
        int bB2 = __shfl(sidx[pB], 2, 32), bB3 = __shfl(sidx[pB], 3, 32);

        half8 vA0 = *(const half8*)(const void*)((0 < lenA) ? Hin + (size_t)bA0 * HROW + sl * 8 : zr);
        half8 vA1 = *(const half8*)(const void*)((1 < lenA) ? Hin + (size_t)bA1 * HROW + sl * 8 : zr);
        half8 vA2 = *(const half8*)(const void*)((2 < lenA) ? Hin + (size_t)bA2 * HROW + sl * 8 : zr);
        half8 vA3 = *(const half8*)(const void*)((3 < lenA) ? Hin + (size_t)bA3 * HROW + sl * 8 : zr);
        half8 vB0 = *(const half8*)(const void*)((0 < lenB) ? Hin + (size_t)bB0 * HROW + sl * 8 : zr);
        half8 vB1 = *(const half8*)(const void*)((1 < lenB) ? Hin + (size_t)bB1 * HROW + sl * 8 : zr);
        half8 vB2 = *(const half8*)(const void*)((2 < lenB) ? Hin + (size_t)bB2 * HROW + sl * 8 : zr);
        half8 vB3 = *(const half8*)(const void*)((3 < lenB) ? Hin + (size_t)bB3 * HROW + sl * 8 : zr);

        float2 acA[4], acB[4];
#pragma unroll
        for (int j = 0; j < 4; ++j) {
            acA[j].x = 0.f; acA[j].y = 0.f;
            acB[j].x = 0.f; acB[j].y = 0.f;
        }
#pragma unroll
        for (int j = 0; j < 4; ++j) {
            acA[j].x += (float)vA0[2 * j] + (float)vA1[2 * j] + (float)vA2[2 * j] + (float)vA3[2 * j];
            acA[j].y += (float)vA0[2 * j + 1] + (float)vA1[2 * j + 1] + (float)vA2[2 * j + 1] + (float)vA3[2 * j + 1];
            acB[j].x += (float)vB0[2 * j] + (float)vB1[2 * j] + (float)vB2[2 * j] + (float)vB3[2 * j];
            acB[j].y += (float)vB0[2 * j + 1] + (float)vB1[2 * j + 1] + (float)vB2[2 * j + 1] + (float)vB3[2 * j + 1];
        }

        if (maxA > 4) {
            for (int e = 4; e < maxA; e += 4) {
                half8 v[4];
#pragma unroll
                for (int u = 0; u < 4; ++u) {
                    int s_ = __shfl(sidx[pA], e + u, 32);
                    v[u] = *(const half8*)(const void*)(
                        ((e + u) < lenA) ? Hin + (size_t)s_ * HROW + sl * 8 : zr);
                }
#pragma unroll
                for (int u = 0; u < 4; ++u) {
#pragma unroll
                    for (int j = 0; j < 4; ++j) {
                        acA[j].x += (float)v[u][2 * j];
                        acA[j].y += (float)v[u][2 * j + 1];
                    }
                }
            }
        }
        if (maxB > 4) {
            for (int e = 4; e < maxB; e += 4) {
                half8 v[4];
#pragma unroll
                for (int u = 0; u < 4; ++u) {
                    int s_ = __shfl(sidx[pB], e + u, 32);
                    v[u] = *(const half8*)(const void*)(
                        ((e + u) < lenB) ? Hin + (size_t)s_ * HROW + sl * 8 : zr);
                }
#pragma unroll
                for (int u = 0; u < 4; ++u) {
#pragma unroll
                    for (int j = 0; j < 4; ++j) {
                        acB[j].x += (float)v[u][2 * j];
                        acB[j].y += (float)v[u][2 * j + 1];
                    }
                }
            }
        }

        float ivA = 1.0f / fmaxf((float)cnA, 1.0f);
        float ivB = 1.0f / fmaxf((float)cnB, 1.0f);
        __half2 oA[4], oB[4];
#pragma unroll
        for (int j = 0; j < 4; ++j) {
            oA[j] = __floats2half2_rn(acA[j].x * ivA, acA[j].y * ivA);
            oB[j] = __floats2half2_rn(acB[j].x * ivB, acB[j].y * ivB);
        }
        __half* dA = &TM[wv * 4 + pA][hh32 * 256 + sl * 8];   // row stride 1032B: 8B-aligned
        __half* dB = &TM[wv * 4 + pB][hh32 * 256 + sl * 8];
        *(uint2*)dA = *(uint2*)&oA[0];
        *(uint2*)(dA + 4) = *(uint2*)&oA[2];
        *(uint2*)dB = *(uint2*)&oB[0];
        *(uint2*)(dB + 4) = *(uint2*)&oB[2];
    }
    __syncthreads();

    // Phase B: MFMA. wave -> branch b = wv>>1, col-half hh = wv&1
    int b = wv >> 1;
    int hh = wv & 1;
    int quad = lane >> 4;
    int l15 = lane & 15;

    floatx4 acc[4];
#pragma unroll
    for (int t = 0; t < 4; ++t) {
        float bv = bias[l15 * 8 + hh * 4 + t];
        acc[t][0] = bv; acc[t][1] = bv; acc[t][2] = bv; acc[t][3] = bv;
    }

    const __half* hrow = Hin + (size_t)(n0 + l15) * HROW + b * Hh + quad * 8;
#pragma unroll
    for (int s = 0; s < 12; ++s) {
        half8 af;
        if (s < 4)
            af = *(const half8*)(const void*)(hrow + s * 32);
        else
            af = *(const half8*)(const void*)&TM[l15][((s >> 2) - 1) * 256 + b * 128 +
                                                     (s & 3) * 32 + quad * 8];
#pragma unroll
        for (int t = 0; t < 4; ++t) {
            half8 bf = *(const half8*)(const void*)(
                Bsw + ((size_t)((hh * 4 + t) * 12 + s) * 64 + lane) * 8);
            acc[t] = __builtin_amdgcn_mfma_f32_16x16x32_f16(af, bf, acc[t], 0, 0, 0);
        }
    }

    if (!do_final) {
#pragma unroll
        for (int r = 0; r < 4; ++r) {
            int node = n0 + quad * 4 + r;
            __half2 o[2];
            o[0] = __floats2half2_rn(acc[0][r], acc[1][r]);
            o[1] = __floats2half2_rn(acc[2][r], acc[3][r]);
            *(uint2*)(Hout + (size_t)node * HROW + b * Hh + l15 * 8 + hh * 4) = *(uint2*)o;
        }
    } else {
        __syncthreads();  // all TM reads done before aliased TO writes
#pragma unroll
        for (int r = 0; r < 4; ++r) {
            int nl = quad * 4 + r;
            __half2 o[2];
            o[0] = __floats2half2_rn(acc[0][r], acc[1][r]);
            o[1] = __floats2half2_rn(acc[2][r], acc[3][r]);
            *(uint2*)&TO[nl][b * 128 + l15 * 8 + hh * 4] = *(uint2*)o;
        }
        __syncthreads();
        if (tid < FN * Oo) {
            int node = tid / 3;
            int o3 = tid - node * 3;
            float a = bS[o3], m = bS[o3];
            const __half2* row = (const __half2*)TO[node];
#pragma unroll 4
            for (int k2 = 0; k2 < 64; ++k2) {
                float2 v = __half22float2(row[k2]);
                float2 u = __half22float2(row[64 + k2]);
                float w0 = WoS[(2 * k2) * 3 + o3];
                float w1 = WoS[(2 * k2 + 1) * 3 + o3];
                a += v.x * w0 + v.y * w1;
                m += u.x * w0 + u.y * w1;
            }
            out[(size_t)(n0 + node) * 3 + o3] = a * m;
        }
    }
}

// ================= host =================
extern "C" void kernel_launch(void* const* d_in, const int* in_sizes, int n_in,
                              void* d_out, int out_size, void* d_ws, size_t ws_size,
                              hipStream_t stream) {
    const float* mf = (const float*)d_in[0];
    const float* ff = (const float*)d_in[1];
    const float* W1 = (const float*)d_in[2];
    const float* b1 = (const float*)d_in[3];
    const float* rg1_w = (const float*)d_in[4];
    const float* rg1_root = (const float*)d_in[5];
    const float* rg1_b = (const float*)d_in[6];
    const float* rg2_w = (const float*)d_in[7];
    const float* rg2_root = (const float*)d_in[8];
    const float* rg2_b = (const float*)d_in[9];
    const float* Wo = (const float*)d_in[10];
    const float* bo = (const float*)d_in[11];
    const int* ei = (const int*)d_in[12];
    const int* et = (const int*)d_in[13];
    float* out = (float*)d_out;

    const size_t szBsw = (size_t)8 * 12 * 64 * 8 * 2;  // 96 KB

    // layout for a given bucket capacity; cnt region carries a 512B zero-row tail
    auto layoutNeed = [&](int cap, size_t* offs) {
        size_t o = 0;
        auto take = [&](size_t bytes) { size_t r = o; o += (bytes + 15) & ~(size_t)15; return r; };
        offs[0] = take((size_t)Mm * 4 + 512);        // cnt + zero-row
        offs[1] = take((size_t)Mm * cap * 4);        // eidx (fixed-capacity buckets)
        offs[2] = take(szBsw);                       // Bsw1
        offs[3] = take(szBsw);                       // Bsw2
        offs[4] = take((size_t)Nn * HROW * 2);       // H0
        offs[5] = take((size_t)Nn * HROW * 2);       // H1
        offs[6] = take((size_t)Hh * Dd * 4);         // W1T (8 KB)
        return o;
    };

    size_t offs[7];
    int cap = 64;                                    // ~154.7 MB (proven ws >= ~159.6 MB)
    size_t NEED = layoutNeed(cap, offs);
    if (ws_size < NEED) {
        cap = 32;                                    // ~129.1 MB fallback
        NEED = layoutNeed(cap, offs);
        if (ws_size < NEED) {
            k_diag<<<1, 1, 0, stream>>>(out, (float)ws_size);
            return;
        }
    }

    int* cnt = (int*)((char*)d_ws + offs[0]);
    int* eidx = (int*)((char*)d_ws + offs[1]);
    __half* Bsw1 = (__half*)((char*)d_ws + offs[2]);
    __half* Bsw2 = (__half*)((char*)d_ws + offs[3]);
    __half* H0 = (__half*)((char*)d_ws + offs[4]);
    __half* H1 = (__half*)((char*)d_ws + offs[5]);
    float* W1T = (float*)((char*)d_ws + offs[6]);
    const __half* zrow = (const __half*)((char*)d_ws + offs[0] + (size_t)Mm * 4);

    // 4-dispatch pipeline (memset + W1T transpose fused into k_init)
    k_init<<<(NZ16 + 255) / 256, 256, 0, stream>>>((int4*)cnt, W1, W1T);
    k_prep_all<<<INTB2 + CNTB + SWB, 256, 0, stream>>>(ei, et, cnt, eidx, cap,
                                                       rg1_root, rg1_w, rg2_root, rg2_w,
                                                       Bsw1, Bsw2, mf, ff, W1T, b1, H0);
    k_conv_f<<<Nn / FN, 256, 0, stream>>>(H0, H1, cnt, eidx, cap, Bsw1, rg1_b, zrow,
                                          0, nullptr, nullptr, nullptr);
    k_conv_f<<<Nn / FN, 256, 0, stream>>>(H1, H0, cnt, eidx, cap, Bsw2, rg2_b, zrow,
                                          1, Wo, bo, out);
}